// Round 11
// baseline (895.295 us; speedup 1.0000x reference)
//
#include <hip/hip_runtime.h>

#define EPS_BN 1e-4f
constexpr int BLK = 256;
constexpr int NCOPY = 8;     // stats atomic copies

// ---------- fine rulebook: row-major exact, stride 27 ----------
__global__ __launch_bounds__(64) void build_fine_k(
    const int* __restrict__ nbr, int n, int* __restrict__ cnt, int* __restrict__ ent) {
  int i = blockIdx.x * 64 + threadIdx.x;
  if (i >= n) return;
  int c = 0;
  const int* nr = nbr + (size_t)i * 27;
  int* er = ent + (size_t)i * 27;
#pragma unroll 1
  for (int k = 0; k < 27; ++k) {
    int j = nr[k];
    if (j >= 0) er[c++] = (k << 18) | j;
  }
  cnt[i] = c;
}

__global__ __launch_bounds__(BLK) void child_scatter_k(
    const int* __restrict__ parent, const int* __restrict__ offid, int n,
    int* __restrict__ ccnt, int* __restrict__ cent) {
  int i = blockIdx.x * BLK + threadIdx.x;
  if (i >= n) return;
  int p = parent[i];
  int slot = atomicAdd(&ccnt[p], 1);
  cent[p * 8 + slot] = i | (offid[i] << 25);
}

// ---------- coarse k-sort rulebook: count -> padded prefix -> scatter ----------
__global__ __launch_bounds__(BLK) void kcount_k(
    const int* __restrict__ nbr, int n, int* __restrict__ kcnt) {
  __shared__ int lc[27];
  int t = threadIdx.x;
  if (t < 27) lc[t] = 0;
  __syncthreads();
  int i = blockIdx.x * BLK + t;
  if (i < n) {
#pragma unroll 1
    for (int k = 0; k < 27; ++k)
      if (nbr[(size_t)i * 27 + k] >= 0) atomicAdd(&lc[k], 1);
  }
  __syncthreads();
  if (t < 27 && lc[t]) atomicAdd(&kcnt[t], lc[t]);
}

__global__ void kprefix_k(const int* __restrict__ kcnt,
                          int* __restrict__ segSt, int* __restrict__ kfill) {
  if (threadIdx.x == 0) {
    int s = 0;
#pragma unroll 1
    for (int k = 0; k < 27; ++k) {
      segSt[k] = s; kfill[k] = s;
      s += (kcnt[k] + 127) & ~127;
    }
    segSt[27] = s;
  }
}

__global__ __launch_bounds__(BLK) void kscatter_k(
    const int* __restrict__ nbr, int n, int* __restrict__ kfill,
    int* __restrict__ entJ, int* __restrict__ cntC, int* __restrict__ posC) {
  int i = blockIdx.x * BLK + threadIdx.x;
  if (i >= n) return;
  int c = 0;
#pragma unroll 1
  for (int k = 0; k < 27; ++k) {
    int j = nbr[(size_t)i * 27 + k];
    if (j >= 0) {
      int pos = atomicAdd(&kfill[k], 1);
      entJ[pos] = j;
      posC[(size_t)i * 27 + c] = pos;
      ++c;
    }
  }
  cntC[i] = c;
}

__device__ __forceinline__ unsigned f2bf(float x) {
  unsigned u = __float_as_uint(x);
  return (u + 0x7FFFu + ((u >> 16) & 1u)) >> 16;
}

// ---------- pass 1: k-uniform pair GEMM, 8x8 register tile, bf16 partials ----------
__global__ __launch_bounds__(128) void pgemm_k(
    const float* __restrict__ in, const int* __restrict__ segSt,
    const int* __restrict__ entJ,
    const float* __restrict__ sums, const float* __restrict__ gm,
    const float* __restrict__ bt, float invn,
    const float* __restrict__ W, unsigned short* __restrict__ partials) {
  __shared__ float lw[4096];
  __shared__ float lx[128 * 68];
  __shared__ float lst[128];
  int t = threadIdx.x;
  int base = blockIdx.x * 128;
  if (base >= segSt[27]) return;
  int k = 0;
#pragma unroll 1
  while (segSt[k + 1] <= base) ++k;
  // BN finalize
  if (t < 64) {
    float s = 0.f, q = 0.f;
#pragma unroll
    for (int cp = 0; cp < NCOPY; ++cp) { s += sums[cp * 128 + t]; q += sums[cp * 128 + 64 + t]; }
    float mu = s * invn, var = q * invn - mu * mu;
    float sc = gm[t] / sqrtf(var + EPS_BN);
    lst[t] = sc; lst[64 + t] = bt[t] - mu * sc;
  }
  // stage W[k]
  const float4* wsrc = reinterpret_cast<const float4*>(W + (size_t)k * 4096);
#pragma unroll
  for (int q = 0; q < 8; ++q)
    reinterpret_cast<float4*>(lw)[t + q * 128] = wsrc[t + q * 128];
  __syncthreads();
  // stage X rows with BN+ReLU
#pragma unroll 1
  for (int it = 0; it < 16; ++it) {
    int idx = t + it * 128;
    int pr = idx >> 4, cq = idx & 15;
    int j = entJ[base + pr];
    float4 x = *reinterpret_cast<const float4*>(in + (size_t)j * 64 + cq * 4);
    int cb = cq * 4;
    float y0 = fmaf(x.x, lst[cb + 0], lst[64 + cb + 0]);
    float y1 = fmaf(x.y, lst[cb + 1], lst[64 + cb + 1]);
    float y2 = fmaf(x.z, lst[cb + 2], lst[64 + cb + 2]);
    float y3 = fmaf(x.w, lst[cb + 3], lst[64 + cb + 3]);
    *reinterpret_cast<float4*>(&lx[pr * 68 + cb]) =
        make_float4(y0 > 0.f ? y0 : 0.f, y1 > 0.f ? y1 : 0.f,
                    y2 > 0.f ? y2 : 0.f, y3 > 0.f ? y3 : 0.f);
  }
  __syncthreads();
  // GEMM: slot of 8 lanes, 8 pairs x 8 cols per thread
  int slot = t >> 3, g = (t & 7) * 8;
  float acc[8][8];
#pragma unroll
  for (int pp = 0; pp < 8; ++pp)
#pragma unroll
    for (int b = 0; b < 8; ++b) acc[pp][b] = 0.f;
#pragma unroll
  for (int c4 = 0; c4 < 16; ++c4) {
    int cb = c4 * 4;
    float4 xq[8];
#pragma unroll
    for (int pp = 0; pp < 8; ++pp)
      xq[pp] = *reinterpret_cast<const float4*>(&lx[(slot + 16 * pp) * 68 + cb]);
#pragma unroll
    for (int q = 0; q < 4; ++q) {
      float4 wa = *reinterpret_cast<const float4*>(&lw[(cb + q) * 64 + g]);
      float4 wb = *reinterpret_cast<const float4*>(&lw[(cb + q) * 64 + g + 4]);
      float ws[8] = {wa.x, wa.y, wa.z, wa.w, wb.x, wb.y, wb.z, wb.w};
#pragma unroll
      for (int pp = 0; pp < 8; ++pp) {
        float xv = q == 0 ? xq[pp].x : (q == 1 ? xq[pp].y : (q == 2 ? xq[pp].z : xq[pp].w));
#pragma unroll
        for (int b = 0; b < 8; ++b) acc[pp][b] = fmaf(xv, ws[b], acc[pp][b]);
      }
    }
  }
  // store bf16 partials
#pragma unroll
  for (int pp = 0; pp < 8; ++pp) {
    int p = base + slot + 16 * pp;
    uint4 o;
    o.x = f2bf(acc[pp][0]) | (f2bf(acc[pp][1]) << 16);
    o.y = f2bf(acc[pp][2]) | (f2bf(acc[pp][3]) << 16);
    o.z = f2bf(acc[pp][4]) | (f2bf(acc[pp][5]) << 16);
    o.w = f2bf(acc[pp][6]) | (f2bf(acc[pp][7]) << 16);
    *reinterpret_cast<uint4*>(partials + ((size_t)p * 64 + g)) = o;
  }
}

// ---------- pass 2: gather partials per row, fused stats ----------
__global__ __launch_bounds__(BLK) void pgather_k(
    const unsigned short* __restrict__ partials, const int* __restrict__ cntC,
    const int* __restrict__ posC, float* __restrict__ out, int nc,
    float* __restrict__ osums) {
  __shared__ float red[256];
  int t = threadIdx.x;
  for (int idx = t; idx < 256; idx += BLK) red[idx] = 0.f;
  __syncthreads();
  int slot = t >> 4, g = (t & 15) * 4;
  int row = blockIdx.x * 16 + slot;
  float a0 = 0.f, a1 = 0.f, a2 = 0.f, a3 = 0.f;
  if (row < nc) {
    int c = cntC[row];
    const int* pr = posC + (size_t)row * 27;
#pragma unroll 1
    for (int e = 0; e < c; ++e) {
      int pos = pr[e];
      uint2 u = *reinterpret_cast<const uint2*>(partials + ((size_t)pos * 64 + g));
      a0 += __uint_as_float(u.x << 16);
      a1 += __uint_as_float(u.x & 0xFFFF0000u);
      a2 += __uint_as_float(u.y << 16);
      a3 += __uint_as_float(u.y & 0xFFFF0000u);
    }
    *reinterpret_cast<float4*>(out + (size_t)row * 64 + g) = make_float4(a0, a1, a2, a3);
  }
  atomicAdd(&red[g + 0], a0); atomicAdd(&red[g + 1], a1);
  atomicAdd(&red[g + 2], a2); atomicAdd(&red[g + 3], a3);
  atomicAdd(&red[128 + g + 0], a0 * a0); atomicAdd(&red[128 + g + 1], a1 * a1);
  atomicAdd(&red[128 + g + 2], a2 * a2); atomicAdd(&red[128 + g + 3], a3 * a3);
  __syncthreads();
  int copy = blockIdx.x & (NCOPY - 1);
  if (t < 128) {
    int half = t >> 6, ch = t & 63;
    atomicAdd(&osums[copy * 128 + half * 64 + ch], red[half * 128 + ch]);
  }
}

// ---------- Type A (R6-proven): output-stationary register-acc gather ----------
template <int CI, int CO, int MODE>
__global__ __launch_bounds__(BLK) void tconvA_k(
    const float* __restrict__ in, const int* __restrict__ ent, const int* __restrict__ cnt,
    const int* __restrict__ parent, const int* __restrict__ offid,
    const float* __restrict__ W, float* __restrict__ out, int n,
    float* __restrict__ osums) {
  constexpr int LANES = CO / 4, SLOTS = BLK / LANES, RPS = 64 / SLOTS;
  __shared__ float red[2 * CO];
  int t = threadIdx.x;
  for (int idx = t; idx < 2 * CO; idx += BLK) red[idx] = 0.f;
  __syncthreads();
  int slot = t / LANES, lane = t % LANES, g = lane * 4;
  int T = blockIdx.x;
  float ssum[4] = {0, 0, 0, 0}, ssq[4] = {0, 0, 0, 0};
#pragma unroll 1
  for (int rr = 0; rr < RPS; ++rr) {
    int row = T * 64 + slot * RPS + rr;
    bool vrow = row < n;
    float a0 = 0.f, a1 = 0.f, a2 = 0.f, a3 = 0.f;
    int ec = 0;
    if (vrow) ec = (MODE == 2) ? 1 : cnt[row];
#pragma unroll 1
    for (int e = 0; e < ec; ++e) {
      int k, j;
      if constexpr (MODE == 0) {
        int v = ent[(size_t)row * 27 + e];
        k = (v >> 18) & 31; j = v & 0x3FFFF;
      } else if constexpr (MODE == 1) {
        int v = ent[(size_t)row * 8 + e];
        k = v >> 25; j = v & 0x1FFFFFF;
      } else {
        k = offid[row]; j = parent[row];
      }
      const float* Wk = W + (size_t)k * (CI * CO) + g;
      const float* xr = in + (size_t)j * CI;
#pragma unroll
      for (int h = 0; h < CI / 32; ++h) {
        float4 xv[8];
#pragma unroll
        for (int c4 = 0; c4 < 8; ++c4)
          xv[c4] = *reinterpret_cast<const float4*>(xr + h * 32 + c4 * 4);
#pragma unroll
        for (int c4 = 0; c4 < 8; ++c4) {
          float xs[4] = {xv[c4].x, xv[c4].y, xv[c4].z, xv[c4].w};
#pragma unroll
          for (int q = 0; q < 4; ++q) {
            float4 wv = *reinterpret_cast<const float4*>(Wk + (size_t)(h * 32 + c4 * 4 + q) * CO);
            a0 = fmaf(xs[q], wv.x, a0);
            a1 = fmaf(xs[q], wv.y, a1);
            a2 = fmaf(xs[q], wv.z, a2);
            a3 = fmaf(xs[q], wv.w, a3);
          }
        }
      }
    }
    if (vrow)
      *reinterpret_cast<float4*>(out + (size_t)row * CO + g) = make_float4(a0, a1, a2, a3);
    ssum[0] += a0; ssum[1] += a1; ssum[2] += a2; ssum[3] += a3;
    ssq[0] = fmaf(a0, a0, ssq[0]); ssq[1] = fmaf(a1, a1, ssq[1]);
    ssq[2] = fmaf(a2, a2, ssq[2]); ssq[3] = fmaf(a3, a3, ssq[3]);
  }
#pragma unroll
  for (int q = 0; q < 4; ++q) {
    atomicAdd(&red[g + q], ssum[q]);
    atomicAdd(&red[CO + g + q], ssq[q]);
  }
  __syncthreads();
  int copy = blockIdx.x & (NCOPY - 1);
  if (t < 2 * CO) atomicAdd(&osums[copy * 2 * CO + t], red[t]);
}

// ---------- bnact: finalize(8 copies) + relu(x*scale+shift) ----------
template <int C>
__global__ __launch_bounds__(BLK) void bnact_k(
    const float* __restrict__ in, const float* __restrict__ sums,
    const float* __restrict__ gm, const float* __restrict__ bt, float invn,
    float* __restrict__ outp, int n) {
  __shared__ float lst[2 * C];
  int t = threadIdx.x;
  if (t < C) {
    float s = 0.f, q = 0.f;
#pragma unroll
    for (int cp = 0; cp < NCOPY; ++cp) { s += sums[cp * 2 * C + t]; q += sums[cp * 2 * C + C + t]; }
    float mu = s * invn, var = q * invn - mu * mu;
    float sc = gm[t] / sqrtf(var + EPS_BN);
    lst[t] = sc; lst[C + t] = bt[t] - mu * sc;
  }
  __syncthreads();
  int total = n * (C / 4);
  const float4* in4 = reinterpret_cast<const float4*>(in);
  float4* out4 = reinterpret_cast<float4*>(outp);
  for (int idx = blockIdx.x * BLK + t; idx < total; idx += gridDim.x * BLK) {
    int cb = (idx & (C / 4 - 1)) * 4;
    float4 x = in4[idx];
    float v[4] = {x.x, x.y, x.z, x.w};
#pragma unroll
    for (int q = 0; q < 4; ++q) {
      float y = fmaf(v[q], lst[cb + q], lst[C + cb + q]);
      v[q] = y > 0.f ? y : 0.f;
    }
    out4[idx] = make_float4(v[0], v[1], v[2], v[3]);
  }
}

// ---------- bncat: concat(bn(f2), bn(u)) -> acat [N,64] ----------
__global__ __launch_bounds__(BLK) void bncat_k(
    const float* __restrict__ fa, const float* __restrict__ sA,
    const float* __restrict__ gA, const float* __restrict__ bA,
    const float* __restrict__ fb, const float* __restrict__ sB,
    const float* __restrict__ gB, const float* __restrict__ bB,
    float invn, float* __restrict__ acat, int n) {
  __shared__ float lst[128];
  int t = threadIdx.x;
  if (t < 64) {
    int half = t >> 5, c = t & 31;
    const float* ss = half ? sB : sA;
    const float* gg = half ? gB : gA;
    const float* bb = half ? bB : bA;
    float s = 0.f, q = 0.f;
#pragma unroll
    for (int cp = 0; cp < NCOPY; ++cp) { s += ss[cp * 64 + c]; q += ss[cp * 64 + 32 + c]; }
    float mu = s * invn, var = q * invn - mu * mu;
    float sc = gg[c] / sqrtf(var + EPS_BN);
    lst[half * 64 + c] = sc; lst[half * 64 + 32 + c] = bb[c] - mu * sc;
  }
  __syncthreads();
  int total = n * 16;
  for (int idx = blockIdx.x * BLK + t; idx < total; idx += gridDim.x * BLK) {
    int row = idx >> 4, c4 = idx & 15;
    int half = c4 >> 3, cc = (c4 & 7) * 4;
    const float* src = half ? fb : fa;
    float4 x = *reinterpret_cast<const float4*>(src + (size_t)row * 32 + cc);
    const float* L = lst + half * 64;
    float v[4] = {x.x, x.y, x.z, x.w};
#pragma unroll
    for (int q = 0; q < 4; ++q) {
      float y = fmaf(v[q], L[cc + q], L[32 + cc + q]);
      v[q] = y > 0.f ? y : 0.f;
    }
    *reinterpret_cast<float4*>(acat + (size_t)row * 64 + c4 * 4) = make_float4(v[0], v[1], v[2], v[3]);
  }
}

// ---------------- conv_in: [N,3] x [27,3,32] -> [N,32], fused stats ----------------
__global__ __launch_bounds__(BLK) void conv_in_k(
    const float* __restrict__ feat, const int* __restrict__ nbr,
    const float* __restrict__ W, float* __restrict__ out, int n,
    float* __restrict__ osums) {
  int i = blockIdx.x * BLK + threadIdx.x;
  bool valid = i < n;
  float acc[32];
#pragma unroll
  for (int c = 0; c < 32; ++c) acc[c] = 0.f;
#pragma unroll 1
  for (int k = 0; k < 27; ++k) {
    int j = valid ? nbr[(size_t)i * 27 + k] : -1;
    if (j < 0) continue;
    float x0 = feat[j * 3 + 0], x1 = feat[j * 3 + 1], x2 = feat[j * 3 + 2];
    const float* w0 = W + k * 96;
#pragma unroll
    for (int co = 0; co < 8; ++co) {
      float4 a = *reinterpret_cast<const float4*>(w0 + co * 4);
      float4 b = *reinterpret_cast<const float4*>(w0 + 32 + co * 4);
      float4 cc = *reinterpret_cast<const float4*>(w0 + 64 + co * 4);
      acc[4*co+0] = fmaf(x0, a.x, fmaf(x1, b.x, fmaf(x2, cc.x, acc[4*co+0])));
      acc[4*co+1] = fmaf(x0, a.y, fmaf(x1, b.y, fmaf(x2, cc.y, acc[4*co+1])));
      acc[4*co+2] = fmaf(x0, a.z, fmaf(x1, b.z, fmaf(x2, cc.z, acc[4*co+2])));
      acc[4*co+3] = fmaf(x0, a.w, fmaf(x1, b.w, fmaf(x2, cc.w, acc[4*co+3])));
    }
  }
  if (valid) {
    float* o = out + (size_t)i * 32;
#pragma unroll
    for (int co = 0; co < 8; ++co)
      *reinterpret_cast<float4*>(o + co * 4) = make_float4(acc[4*co], acc[4*co+1], acc[4*co+2], acc[4*co+3]);
  }
  __shared__ float red[2][4][32];
  int w = threadIdx.x >> 6;
#pragma unroll
  for (int c = 0; c < 32; ++c) {
    float v = acc[c], q = acc[c] * acc[c];
#pragma unroll
    for (int off = 32; off; off >>= 1) {
      v += __shfl_down(v, off);
      q += __shfl_down(q, off);
    }
    if ((threadIdx.x & 63) == 0) { red[0][w][c] = v; red[1][w][c] = q; }
  }
  __syncthreads();
  if (threadIdx.x < 64) {
    int kind = threadIdx.x >> 5, c = threadIdx.x & 31;
    float s = red[kind][0][c] + red[kind][1][c] + red[kind][2][c] + red[kind][3][c];
    atomicAdd(&osums[(blockIdx.x & (NCOPY - 1)) * 64 + kind * 32 + c], s);
  }
}

// ---------------- head: finalize(8 copies) + bn @ w_lin + b_lin -> [N,50] ----------------
__global__ __launch_bounds__(BLK) void head_k(
    const float* __restrict__ fin, const float* __restrict__ sums,
    const float* __restrict__ gm, const float* __restrict__ bt, float inv_n,
    const float* __restrict__ Wl, const float* __restrict__ bl,
    float* __restrict__ out, int n) {
  __shared__ float lw[32 * 50];
  __shared__ float lb[52];
  __shared__ float lst[64];
  int t = threadIdx.x;
  if (t < 32) {
    float s = 0.f, q = 0.f;
#pragma unroll
    for (int cp = 0; cp < NCOPY; ++cp) { s += sums[cp * 64 + t]; q += sums[cp * 64 + 32 + t]; }
    float mu = s * inv_n, var = q * inv_n - mu * mu;
    float sc = gm[t] / sqrtf(var + EPS_BN);
    lst[t] = sc; lst[32 + t] = bt[t] - mu * sc;
  }
  for (int idx = t; idx < 1600; idx += BLK) lw[idx] = Wl[idx];
  if (t < 50) lb[t] = bl[t];
  __syncthreads();
  int i = blockIdx.x * BLK + t;
  if (i >= n) return;
  float x[32];
  const float* fj = fin + (size_t)i * 32;
#pragma unroll
  for (int c4 = 0; c4 < 8; ++c4) {
    float4 v = *reinterpret_cast<const float4*>(fj + c4 * 4);
    float vs[4] = {v.x, v.y, v.z, v.w};
#pragma unroll
    for (int q = 0; q < 4; ++q) {
      int c = c4 * 4 + q;
      float y = fmaf(vs[q], lst[c], lst[32 + c]);
      x[c] = y > 0.f ? y : 0.f;
    }
  }
  float acc[50];
#pragma unroll
  for (int co = 0; co < 50; ++co) acc[co] = lb[co];
#pragma unroll 4
  for (int c = 0; c < 32; ++c) {
#pragma unroll
    for (int co = 0; co < 50; ++co) acc[co] = fmaf(x[c], lw[c * 50 + co], acc[co]);
  }
  float* o = out + (size_t)i * 50;
#pragma unroll
  for (int co = 0; co < 25; ++co)
    *reinterpret_cast<float2*>(o + co * 2) = make_float2(acc[co * 2], acc[co * 2 + 1]);
}

extern "C" void kernel_launch(void* const* d_in, const int* in_sizes, int n_in,
                              void* d_out, int out_size, void* d_ws, size_t ws_size,
                              hipStream_t stream) {
  const float* feat   = (const float*)d_in[1];
  const int*   nbrF   = (const int*)d_in[2];
  const int*   nbrC   = (const int*)d_in[3];
  const int*   parent = (const int*)d_in[4];
  const int*   offid  = (const int*)d_in[5];
  const float* w_in   = (const float*)d_in[7];
  const float* w_b1   = (const float*)d_in[8];
  const float* w_down = (const float*)d_in[9];
  const float* w_b2   = (const float*)d_in[10];
  const float* w_up   = (const float*)d_in[11];
  const float* w_b3   = (const float*)d_in[12];
  const float* g1v = (const float*)d_in[13], *b1v = (const float*)d_in[14];
  const float* gdv = (const float*)d_in[15], *bdv = (const float*)d_in[16];
  const float* g2v = (const float*)d_in[17], *b2v = (const float*)d_in[18];
  const float* guv = (const float*)d_in[19], *buv = (const float*)d_in[20];
  const float* g3v = (const float*)d_in[21], *b3v = (const float*)d_in[22];
  const float* gov = (const float*)d_in[23], *bov = (const float*)d_in[24];
  const float* w_lin = (const float*)d_in[25];
  const float* b_lin = (const float*)d_in[26];
  float* out = (float*)d_out;

  int N  = in_sizes[4];
  int NC = in_sizes[3] / 27;
  int ntF = (N + 63) / 64, ntC = (NC + 63) / 64;
  int CAPP = ((NC * 9 / 2) / 128 + 28) * 128;   // padded pair capacity

  size_t szF = (size_t)N * 32;
  size_t szG = (size_t)NC * 64;
  size_t SB  = (size_t)N * 64;

  float* ws = (float*)d_ws;
  float* S1 = ws;          // f1 [N,32] -> g2c [NC,64]
  float* S2 = S1 + SB;     // a1 -> acat [N,64]
  float* S3 = S2 + SB;     // f2 [N,32] -> f3 [N,32]
  float* S4 = S3 + szF;    // a2 [N,32] -> u [N,32]
  float* S5 = S4 + szF;    // gC [NC,64] -> au [NC,64]
  float* sums1 = S5 + szG;           // 8*64
  float* sumsD = sums1 + 8 * 64;     // 8*64
  float* sums2 = sumsD + 8 * 64;     // 8*128
  float* sumsU = sums2 + 8 * 128;    // 8*128
  float* sums4 = sumsU + 8 * 128;    // 8*64
  float* sums5 = sums4 + 8 * 64;     // 8*64
  int* ccnt = (int*)(sums5 + 8 * 64);         // NC
  int* cent = ccnt + NC;                      // NC*8
  int* cntF = cent + (size_t)NC * 8;          // N
  int* entF = cntF + N;                       // N*27
  int* kcnt = entF + (size_t)N * 27;          // 32
  int* segSt = kcnt + 32;                     // 32
  int* kfill = segSt + 32;                    // 32
  int* cntC = kfill + 32;                     // NC
  int* posC = cntC + NC;                      // NC*27
  int* entJ = posC + (size_t)NC * 27;         // CAPP
  unsigned short* partials = (unsigned short*)
      (((uintptr_t)(entJ + CAPP) + 15) & ~(uintptr_t)15);  // CAPP*64 bf16

  hipMemsetAsync(sums1, 0, (4096 + NC) * sizeof(float), stream);
  hipMemsetAsync(kcnt, 0, 96 * sizeof(int), stream);
  hipMemsetAsync(entJ, 0, (size_t)CAPP * sizeof(int), stream);

  int gridN = (N + BLK - 1) / BLK;
  int gridC = (NC + BLK - 1) / BLK;
  int agrid = 1024;
  float invN = 1.f / (float)N, invC = 1.f / (float)NC;

  // rulebooks
  build_fine_k<<<ntF, 64, 0, stream>>>(nbrF, N, cntF, entF);
  child_scatter_k<<<gridN, BLK, 0, stream>>>(parent, offid, N, ccnt, cent);
  kcount_k<<<gridC, BLK, 0, stream>>>(nbrC, NC, kcnt);
  kprefix_k<<<1, 32, 0, stream>>>(kcnt, segSt, kfill);
  kscatter_k<<<gridC, BLK, 0, stream>>>(nbrC, NC, kfill, entJ, cntC, posC);

  // conv_in -> f1(S1), stats -> sums1
  conv_in_k<<<gridN, BLK, 0, stream>>>(feat, nbrF, w_in, S1, N, sums1);
  bnact_k<32><<<agrid, BLK, 0, stream>>>(S1, sums1, g1v, b1v, invN, S2, N);   // a1

  // b1: a1 -> f2(S3), stats -> sumsD
  tconvA_k<32, 32, 0><<<ntF, BLK, 0, stream>>>(
      S2, entF, cntF, nullptr, nullptr, w_b1, S3, N, sumsD);
  bnact_k<32><<<agrid, BLK, 0, stream>>>(S3, sumsD, gdv, bdv, invN, S4, N);   // a2

  // down: a2 -> gC(S5), stats -> sums2
  tconvA_k<32, 64, 1><<<ntC, BLK, 0, stream>>>(
      S4, cent, ccnt, nullptr, nullptr, w_down, S5, NC, sums2);

  // b2 pass1: k-uniform pair GEMM (bn2 fused at stage) -> partials
  int gridP1 = CAPP / 128;
  pgemm_k<<<gridP1, 128, 0, stream>>>(
      S5, segSt, entJ, sums2, g2v, b2v, invC, w_b2, partials);
  // b2 pass2: gather partials -> g2c(S1, f1 dead), stats -> sumsU
  pgather_k<<<(NC + 15) / 16, BLK, 0, stream>>>(
      partials, cntC, posC, S1, NC, sumsU);

  bnact_k<64><<<agrid, BLK, 0, stream>>>(S1, sumsU, guv, buv, invC, S5, NC);  // au (gC dead)

  // up: au -> u(S4, a2 dead), stats -> sums4
  tconvA_k<64, 32, 2><<<ntF, BLK, 0, stream>>>(
      S5, nullptr, nullptr, parent, offid, w_up, S4, N, sums4);

  // bncat: (bn(f2)|bn(u)) -> acat(S2, a1 dead)
  bncat_k<<<agrid, BLK, 0, stream>>>(
      S3, sumsD, g3v, b3v, S4, sums4, g3v + 32, b3v + 32, invN, S2, N);

  // b3: acat -> f3(S3, f2 dead), stats -> sums5
  tconvA_k<64, 32, 0><<<ntF, BLK, 0, stream>>>(
      S2, entF, cntF, nullptr, nullptr, w_b3, S3, N, sums5);

  head_k<<<gridN, BLK, 0, stream>>>(S3, sums5, gov, bov, invN, w_lin, b_lin, out, N);
}

// Round 12
// 527.363 us; speedup vs baseline: 1.6977x; 1.6977x over previous
//
#include <hip/hip_runtime.h>

#define EPS_BN 1e-4f
constexpr int BLK = 256;
constexpr int NCOPY = 8;     // stats atomic copies

// ---------- fine rulebook: row-major exact, stride 27 ----------
__global__ __launch_bounds__(64) void build_fine_k(
    const int* __restrict__ nbr, int n, int* __restrict__ cnt, int* __restrict__ ent) {
  int i = blockIdx.x * 64 + threadIdx.x;
  if (i >= n) return;
  int c = 0;
  const int* nr = nbr + (size_t)i * 27;
  int* er = ent + (size_t)i * 27;
#pragma unroll 1
  for (int k = 0; k < 27; ++k) {
    int j = nr[k];
    if (j >= 0) er[c++] = (k << 18) | j;
  }
  cnt[i] = c;
}

__global__ __launch_bounds__(BLK) void child_scatter_k(
    const int* __restrict__ parent, const int* __restrict__ offid, int n,
    int* __restrict__ ccnt, int* __restrict__ cent) {
  int i = blockIdx.x * BLK + threadIdx.x;
  if (i >= n) return;
  int p = parent[i];
  int slot = atomicAdd(&ccnt[p], 1);
  cent[p * 8 + slot] = i | (offid[i] << 25);
}

// ---------- coarse k-sort rulebook: count -> padded prefix -> hierarchical scatter ----------
__global__ __launch_bounds__(BLK) void kcount_k(
    const int* __restrict__ nbr, int n, int* __restrict__ kcnt) {
  __shared__ int lc[27];
  int t = threadIdx.x;
  if (t < 27) lc[t] = 0;
  __syncthreads();
  int i = blockIdx.x * BLK + t;
  if (i < n) {
#pragma unroll 1
    for (int k = 0; k < 27; ++k)
      if (nbr[(size_t)i * 27 + k] >= 0) atomicAdd(&lc[k], 1);
  }
  __syncthreads();
  if (t < 27 && lc[t]) atomicAdd(&kcnt[t], lc[t]);
}

__global__ void kprefix_k(const int* __restrict__ kcnt,
                          int* __restrict__ segSt, int* __restrict__ kfill) {
  if (threadIdx.x == 0) {
    int s = 0;
#pragma unroll 1
    for (int k = 0; k < 27; ++k) {
      segSt[k] = s; kfill[k] = s;
      s += (kcnt[k] + 127) & ~127;
    }
    segSt[27] = s;
  }
}

// hierarchical: LDS count -> one global reservation per k per block -> LDS position assign
__global__ __launch_bounds__(BLK) void kscatter_k(
    const int* __restrict__ nbr, int n, int* __restrict__ kfill,
    int* __restrict__ entJ, int* __restrict__ cntC, int* __restrict__ posC) {
  __shared__ int lc[27], lbase[27];
  int t = threadIdx.x;
  if (t < 27) lc[t] = 0;
  __syncthreads();
  int i = blockIdx.x * BLK + t;
  int c = 0;
  if (i < n) {
#pragma unroll 1
    for (int k = 0; k < 27; ++k) {
      if (nbr[(size_t)i * 27 + k] >= 0) { atomicAdd(&lc[k], 1); ++c; }
    }
  }
  __syncthreads();
  if (t < 27) {
    lbase[t] = lc[t] ? atomicAdd(&kfill[t], lc[t]) : 0;
    lc[t] = 0;   // reuse as in-block fill counter
  }
  __syncthreads();
  if (i < n) {
    int e = 0;
#pragma unroll 1
    for (int k = 0; k < 27; ++k) {
      int j = nbr[(size_t)i * 27 + k];
      if (j >= 0) {
        int pos = lbase[k] + atomicAdd(&lc[k], 1);
        entJ[pos] = j;
        posC[(size_t)i * 27 + e] = pos;
        ++e;
      }
    }
    cntC[i] = c;
  }
}

__device__ __forceinline__ unsigned f2bf(float x) {
  unsigned u = __float_as_uint(x);
  return (u + 0x7FFFu + ((u >> 16) & 1u)) >> 16;
}

// ---------- pass 1: k-uniform pair GEMM, 8x8 register tile, bf16 partials ----------
__global__ __launch_bounds__(128) void pgemm_k(
    const float* __restrict__ in, const int* __restrict__ segSt,
    const int* __restrict__ entJ,
    const float* __restrict__ sums, const float* __restrict__ gm,
    const float* __restrict__ bt, float invn,
    const float* __restrict__ W, unsigned short* __restrict__ partials) {
  __shared__ float lw[4096];
  __shared__ float lx[128 * 68];
  __shared__ float lst[128];
  int t = threadIdx.x;
  int base = blockIdx.x * 128;
  if (base >= segSt[27]) return;
  int k = 0;
#pragma unroll 1
  while (segSt[k + 1] <= base) ++k;
  // BN finalize
  if (t < 64) {
    float s = 0.f, q = 0.f;
#pragma unroll
    for (int cp = 0; cp < NCOPY; ++cp) { s += sums[cp * 128 + t]; q += sums[cp * 128 + 64 + t]; }
    float mu = s * invn, var = q * invn - mu * mu;
    float sc = gm[t] / sqrtf(var + EPS_BN);
    lst[t] = sc; lst[64 + t] = bt[t] - mu * sc;
  }
  // stage W[k]
  const float4* wsrc = reinterpret_cast<const float4*>(W + (size_t)k * 4096);
#pragma unroll
  for (int q = 0; q < 8; ++q)
    reinterpret_cast<float4*>(lw)[t + q * 128] = wsrc[t + q * 128];
  __syncthreads();
  // stage X rows with BN+ReLU
#pragma unroll 1
  for (int it = 0; it < 16; ++it) {
    int idx = t + it * 128;
    int pr = idx >> 4, cq = idx & 15;
    int j = entJ[base + pr];
    float4 x = *reinterpret_cast<const float4*>(in + (size_t)j * 64 + cq * 4);
    int cb = cq * 4;
    float y0 = fmaf(x.x, lst[cb + 0], lst[64 + cb + 0]);
    float y1 = fmaf(x.y, lst[cb + 1], lst[64 + cb + 1]);
    float y2 = fmaf(x.z, lst[cb + 2], lst[64 + cb + 2]);
    float y3 = fmaf(x.w, lst[cb + 3], lst[64 + cb + 3]);
    *reinterpret_cast<float4*>(&lx[pr * 68 + cb]) =
        make_float4(y0 > 0.f ? y0 : 0.f, y1 > 0.f ? y1 : 0.f,
                    y2 > 0.f ? y2 : 0.f, y3 > 0.f ? y3 : 0.f);
  }
  __syncthreads();
  // GEMM: slot of 8 lanes, 8 pairs x 8 cols per thread
  int slot = t >> 3, g = (t & 7) * 8;
  float acc[8][8];
#pragma unroll
  for (int pp = 0; pp < 8; ++pp)
#pragma unroll
    for (int b = 0; b < 8; ++b) acc[pp][b] = 0.f;
#pragma unroll
  for (int c4 = 0; c4 < 16; ++c4) {
    int cb = c4 * 4;
    float4 xq[8];
#pragma unroll
    for (int pp = 0; pp < 8; ++pp)
      xq[pp] = *reinterpret_cast<const float4*>(&lx[(slot + 16 * pp) * 68 + cb]);
#pragma unroll
    for (int q = 0; q < 4; ++q) {
      float4 wa = *reinterpret_cast<const float4*>(&lw[(cb + q) * 64 + g]);
      float4 wb = *reinterpret_cast<const float4*>(&lw[(cb + q) * 64 + g + 4]);
      float ws[8] = {wa.x, wa.y, wa.z, wa.w, wb.x, wb.y, wb.z, wb.w};
#pragma unroll
      for (int pp = 0; pp < 8; ++pp) {
        float xv = q == 0 ? xq[pp].x : (q == 1 ? xq[pp].y : (q == 2 ? xq[pp].z : xq[pp].w));
#pragma unroll
        for (int b = 0; b < 8; ++b) acc[pp][b] = fmaf(xv, ws[b], acc[pp][b]);
      }
    }
  }
  // store bf16 partials
#pragma unroll
  for (int pp = 0; pp < 8; ++pp) {
    int p = base + slot + 16 * pp;
    uint4 o;
    o.x = f2bf(acc[pp][0]) | (f2bf(acc[pp][1]) << 16);
    o.y = f2bf(acc[pp][2]) | (f2bf(acc[pp][3]) << 16);
    o.z = f2bf(acc[pp][4]) | (f2bf(acc[pp][5]) << 16);
    o.w = f2bf(acc[pp][6]) | (f2bf(acc[pp][7]) << 16);
    *reinterpret_cast<uint4*>(partials + ((size_t)p * 64 + g)) = o;
  }
}

// ---------- pass 2: gather partials per row, fused stats ----------
__global__ __launch_bounds__(BLK) void pgather_k(
    const unsigned short* __restrict__ partials, const int* __restrict__ cntC,
    const int* __restrict__ posC, float* __restrict__ out, int nc,
    float* __restrict__ osums) {
  __shared__ float red[256];
  int t = threadIdx.x;
  for (int idx = t; idx < 256; idx += BLK) red[idx] = 0.f;
  __syncthreads();
  int slot = t >> 4, g = (t & 15) * 4;
  int row = blockIdx.x * 16 + slot;
  float a0 = 0.f, a1 = 0.f, a2 = 0.f, a3 = 0.f;
  if (row < nc) {
    int c = cntC[row];
    const int* pr = posC + (size_t)row * 27;
#pragma unroll 1
    for (int e = 0; e < c; ++e) {
      int pos = pr[e];
      uint2 u = *reinterpret_cast<const uint2*>(partials + ((size_t)pos * 64 + g));
      a0 += __uint_as_float(u.x << 16);
      a1 += __uint_as_float(u.x & 0xFFFF0000u);
      a2 += __uint_as_float(u.y << 16);
      a3 += __uint_as_float(u.y & 0xFFFF0000u);
    }
    *reinterpret_cast<float4*>(out + (size_t)row * 64 + g) = make_float4(a0, a1, a2, a3);
  }
  atomicAdd(&red[g + 0], a0); atomicAdd(&red[g + 1], a1);
  atomicAdd(&red[g + 2], a2); atomicAdd(&red[g + 3], a3);
  atomicAdd(&red[128 + g + 0], a0 * a0); atomicAdd(&red[128 + g + 1], a1 * a1);
  atomicAdd(&red[128 + g + 2], a2 * a2); atomicAdd(&red[128 + g + 3], a3 * a3);
  __syncthreads();
  int copy = blockIdx.x & (NCOPY - 1);
  if (t < 128) {
    int half = t >> 6, ch = t & 63;
    atomicAdd(&osums[copy * 128 + half * 64 + ch], red[half * 128 + ch]);
  }
}

// ---------- Type A (R6-proven): output-stationary register-acc gather ----------
template <int CI, int CO, int MODE>
__global__ __launch_bounds__(BLK) void tconvA_k(
    const float* __restrict__ in, const int* __restrict__ ent, const int* __restrict__ cnt,
    const int* __restrict__ parent, const int* __restrict__ offid,
    const float* __restrict__ W, float* __restrict__ out, int n,
    float* __restrict__ osums) {
  constexpr int LANES = CO / 4, SLOTS = BLK / LANES, RPS = 64 / SLOTS;
  __shared__ float red[2 * CO];
  int t = threadIdx.x;
  for (int idx = t; idx < 2 * CO; idx += BLK) red[idx] = 0.f;
  __syncthreads();
  int slot = t / LANES, lane = t % LANES, g = lane * 4;
  int T = blockIdx.x;
  float ssum[4] = {0, 0, 0, 0}, ssq[4] = {0, 0, 0, 0};
#pragma unroll 1
  for (int rr = 0; rr < RPS; ++rr) {
    int row = T * 64 + slot * RPS + rr;
    bool vrow = row < n;
    float a0 = 0.f, a1 = 0.f, a2 = 0.f, a3 = 0.f;
    int ec = 0;
    if (vrow) ec = (MODE == 2) ? 1 : cnt[row];
#pragma unroll 1
    for (int e = 0; e < ec; ++e) {
      int k, j;
      if constexpr (MODE == 0) {
        int v = ent[(size_t)row * 27 + e];
        k = (v >> 18) & 31; j = v & 0x3FFFF;
      } else if constexpr (MODE == 1) {
        int v = ent[(size_t)row * 8 + e];
        k = v >> 25; j = v & 0x1FFFFFF;
      } else {
        k = offid[row]; j = parent[row];
      }
      const float* Wk = W + (size_t)k * (CI * CO) + g;
      const float* xr = in + (size_t)j * CI;
#pragma unroll
      for (int h = 0; h < CI / 32; ++h) {
        float4 xv[8];
#pragma unroll
        for (int c4 = 0; c4 < 8; ++c4)
          xv[c4] = *reinterpret_cast<const float4*>(xr + h * 32 + c4 * 4);
#pragma unroll
        for (int c4 = 0; c4 < 8; ++c4) {
          float xs[4] = {xv[c4].x, xv[c4].y, xv[c4].z, xv[c4].w};
#pragma unroll
          for (int q = 0; q < 4; ++q) {
            float4 wv = *reinterpret_cast<const float4*>(Wk + (size_t)(h * 32 + c4 * 4 + q) * CO);
            a0 = fmaf(xs[q], wv.x, a0);
            a1 = fmaf(xs[q], wv.y, a1);
            a2 = fmaf(xs[q], wv.z, a2);
            a3 = fmaf(xs[q], wv.w, a3);
          }
        }
      }
    }
    if (vrow)
      *reinterpret_cast<float4*>(out + (size_t)row * CO + g) = make_float4(a0, a1, a2, a3);
    ssum[0] += a0; ssum[1] += a1; ssum[2] += a2; ssum[3] += a3;
    ssq[0] = fmaf(a0, a0, ssq[0]); ssq[1] = fmaf(a1, a1, ssq[1]);
    ssq[2] = fmaf(a2, a2, ssq[2]); ssq[3] = fmaf(a3, a3, ssq[3]);
  }
#pragma unroll
  for (int q = 0; q < 4; ++q) {
    atomicAdd(&red[g + q], ssum[q]);
    atomicAdd(&red[CO + g + q], ssq[q]);
  }
  __syncthreads();
  int copy = blockIdx.x & (NCOPY - 1);
  if (t < 2 * CO) atomicAdd(&osums[copy * 2 * CO + t], red[t]);
}

// ---------- bnact: finalize(8 copies) + relu(x*scale+shift) ----------
template <int C>
__global__ __launch_bounds__(BLK) void bnact_k(
    const float* __restrict__ in, const float* __restrict__ sums,
    const float* __restrict__ gm, const float* __restrict__ bt, float invn,
    float* __restrict__ outp, int n) {
  __shared__ float lst[2 * C];
  int t = threadIdx.x;
  if (t < C) {
    float s = 0.f, q = 0.f;
#pragma unroll
    for (int cp = 0; cp < NCOPY; ++cp) { s += sums[cp * 2 * C + t]; q += sums[cp * 2 * C + C + t]; }
    float mu = s * invn, var = q * invn - mu * mu;
    float sc = gm[t] / sqrtf(var + EPS_BN);
    lst[t] = sc; lst[C + t] = bt[t] - mu * sc;
  }
  __syncthreads();
  int total = n * (C / 4);
  const float4* in4 = reinterpret_cast<const float4*>(in);
  float4* out4 = reinterpret_cast<float4*>(outp);
  for (int idx = blockIdx.x * BLK + t; idx < total; idx += gridDim.x * BLK) {
    int cb = (idx & (C / 4 - 1)) * 4;
    float4 x = in4[idx];
    float v[4] = {x.x, x.y, x.z, x.w};
#pragma unroll
    for (int q = 0; q < 4; ++q) {
      float y = fmaf(v[q], lst[cb + q], lst[C + cb + q]);
      v[q] = y > 0.f ? y : 0.f;
    }
    out4[idx] = make_float4(v[0], v[1], v[2], v[3]);
  }
}

// ---------- bncat: concat(bn(f2), bn(u)) -> acat [N,64] ----------
__global__ __launch_bounds__(BLK) void bncat_k(
    const float* __restrict__ fa, const float* __restrict__ sA,
    const float* __restrict__ gA, const float* __restrict__ bA,
    const float* __restrict__ fb, const float* __restrict__ sB,
    const float* __restrict__ gB, const float* __restrict__ bB,
    float invn, float* __restrict__ acat, int n) {
  __shared__ float lst[128];
  int t = threadIdx.x;
  if (t < 64) {
    int half = t >> 5, c = t & 31;
    const float* ss = half ? sB : sA;
    const float* gg = half ? gB : gA;
    const float* bb = half ? bB : bA;
    float s = 0.f, q = 0.f;
#pragma unroll
    for (int cp = 0; cp < NCOPY; ++cp) { s += ss[cp * 64 + c]; q += ss[cp * 64 + 32 + c]; }
    float mu = s * invn, var = q * invn - mu * mu;
    float sc = gg[c] / sqrtf(var + EPS_BN);
    lst[half * 64 + c] = sc; lst[half * 64 + 32 + c] = bb[c] - mu * sc;
  }
  __syncthreads();
  int total = n * 16;
  for (int idx = blockIdx.x * BLK + t; idx < total; idx += gridDim.x * BLK) {
    int row = idx >> 4, c4 = idx & 15;
    int half = c4 >> 3, cc = (c4 & 7) * 4;
    const float* src = half ? fb : fa;
    float4 x = *reinterpret_cast<const float4*>(src + (size_t)row * 32 + cc);
    const float* L = lst + half * 64;
    float v[4] = {x.x, x.y, x.z, x.w};
#pragma unroll
    for (int q = 0; q < 4; ++q) {
      float y = fmaf(v[q], L[cc + q], L[32 + cc + q]);
      v[q] = y > 0.f ? y : 0.f;
    }
    *reinterpret_cast<float4*>(acat + (size_t)row * 64 + c4 * 4) = make_float4(v[0], v[1], v[2], v[3]);
  }
}

// ---------------- conv_in: [N,3] x [27,3,32] -> [N,32], fused stats ----------------
__global__ __launch_bounds__(BLK) void conv_in_k(
    const float* __restrict__ feat, const int* __restrict__ nbr,
    const float* __restrict__ W, float* __restrict__ out, int n,
    float* __restrict__ osums) {
  int i = blockIdx.x * BLK + threadIdx.x;
  bool valid = i < n;
  float acc[32];
#pragma unroll
  for (int c = 0; c < 32; ++c) acc[c] = 0.f;
#pragma unroll 1
  for (int k = 0; k < 27; ++k) {
    int j = valid ? nbr[(size_t)i * 27 + k] : -1;
    if (j < 0) continue;
    float x0 = feat[j * 3 + 0], x1 = feat[j * 3 + 1], x2 = feat[j * 3 + 2];
    const float* w0 = W + k * 96;
#pragma unroll
    for (int co = 0; co < 8; ++co) {
      float4 a = *reinterpret_cast<const float4*>(w0 + co * 4);
      float4 b = *reinterpret_cast<const float4*>(w0 + 32 + co * 4);
      float4 cc = *reinterpret_cast<const float4*>(w0 + 64 + co * 4);
      acc[4*co+0] = fmaf(x0, a.x, fmaf(x1, b.x, fmaf(x2, cc.x, acc[4*co+0])));
      acc[4*co+1] = fmaf(x0, a.y, fmaf(x1, b.y, fmaf(x2, cc.y, acc[4*co+1])));
      acc[4*co+2] = fmaf(x0, a.z, fmaf(x1, b.z, fmaf(x2, cc.z, acc[4*co+2])));
      acc[4*co+3] = fmaf(x0, a.w, fmaf(x1, b.w, fmaf(x2, cc.w, acc[4*co+3])));
    }
  }
  if (valid) {
    float* o = out + (size_t)i * 32;
#pragma unroll
    for (int co = 0; co < 8; ++co)
      *reinterpret_cast<float4*>(o + co * 4) = make_float4(acc[4*co], acc[4*co+1], acc[4*co+2], acc[4*co+3]);
  }
  __shared__ float red[2][4][32];
  int w = threadIdx.x >> 6;
#pragma unroll
  for (int c = 0; c < 32; ++c) {
    float v = acc[c], q = acc[c] * acc[c];
#pragma unroll
    for (int off = 32; off; off >>= 1) {
      v += __shfl_down(v, off);
      q += __shfl_down(q, off);
    }
    if ((threadIdx.x & 63) == 0) { red[0][w][c] = v; red[1][w][c] = q; }
  }
  __syncthreads();
  if (threadIdx.x < 64) {
    int kind = threadIdx.x >> 5, c = threadIdx.x & 31;
    float s = red[kind][0][c] + red[kind][1][c] + red[kind][2][c] + red[kind][3][c];
    atomicAdd(&osums[(blockIdx.x & (NCOPY - 1)) * 64 + kind * 32 + c], s);
  }
}

// ---------------- head: finalize(8 copies) + bn @ w_lin + b_lin -> [N,50] ----------------
__global__ __launch_bounds__(BLK) void head_k(
    const float* __restrict__ fin, const float* __restrict__ sums,
    const float* __restrict__ gm, const float* __restrict__ bt, float inv_n,
    const float* __restrict__ Wl, const float* __restrict__ bl,
    float* __restrict__ out, int n) {
  __shared__ float lw[32 * 50];
  __shared__ float lb[52];
  __shared__ float lst[64];
  int t = threadIdx.x;
  if (t < 32) {
    float s = 0.f, q = 0.f;
#pragma unroll
    for (int cp = 0; cp < NCOPY; ++cp) { s += sums[cp * 64 + t]; q += sums[cp * 64 + 32 + t]; }
    float mu = s * inv_n, var = q * inv_n - mu * mu;
    float sc = gm[t] / sqrtf(var + EPS_BN);
    lst[t] = sc; lst[32 + t] = bt[t] - mu * sc;
  }
  for (int idx = t; idx < 1600; idx += BLK) lw[idx] = Wl[idx];
  if (t < 50) lb[t] = bl[t];
  __syncthreads();
  int i = blockIdx.x * BLK + t;
  if (i >= n) return;
  float x[32];
  const float* fj = fin + (size_t)i * 32;
#pragma unroll
  for (int c4 = 0; c4 < 8; ++c4) {
    float4 v = *reinterpret_cast<const float4*>(fj + c4 * 4);
    float vs[4] = {v.x, v.y, v.z, v.w};
#pragma unroll
    for (int q = 0; q < 4; ++q) {
      int c = c4 * 4 + q;
      float y = fmaf(vs[q], lst[c], lst[32 + c]);
      x[c] = y > 0.f ? y : 0.f;
    }
  }
  float acc[50];
#pragma unroll
  for (int co = 0; co < 50; ++co) acc[co] = lb[co];
#pragma unroll 4
  for (int c = 0; c < 32; ++c) {
#pragma unroll
    for (int co = 0; co < 50; ++co) acc[co] = fmaf(x[c], lw[c * 50 + co], acc[co]);
  }
  float* o = out + (size_t)i * 50;
#pragma unroll
  for (int co = 0; co < 25; ++co)
    *reinterpret_cast<float2*>(o + co * 2) = make_float2(acc[co * 2], acc[co * 2 + 1]);
}

extern "C" void kernel_launch(void* const* d_in, const int* in_sizes, int n_in,
                              void* d_out, int out_size, void* d_ws, size_t ws_size,
                              hipStream_t stream) {
  const float* feat   = (const float*)d_in[1];
  const int*   nbrF   = (const int*)d_in[2];
  const int*   nbrC   = (const int*)d_in[3];
  const int*   parent = (const int*)d_in[4];
  const int*   offid  = (const int*)d_in[5];
  const float* w_in   = (const float*)d_in[7];
  const float* w_b1   = (const float*)d_in[8];
  const float* w_down = (const float*)d_in[9];
  const float* w_b2   = (const float*)d_in[10];
  const float* w_up   = (const float*)d_in[11];
  const float* w_b3   = (const float*)d_in[12];
  const float* g1v = (const float*)d_in[13], *b1v = (const float*)d_in[14];
  const float* gdv = (const float*)d_in[15], *bdv = (const float*)d_in[16];
  const float* g2v = (const float*)d_in[17], *b2v = (const float*)d_in[18];
  const float* guv = (const float*)d_in[19], *buv = (const float*)d_in[20];
  const float* g3v = (const float*)d_in[21], *b3v = (const float*)d_in[22];
  const float* gov = (const float*)d_in[23], *bov = (const float*)d_in[24];
  const float* w_lin = (const float*)d_in[25];
  const float* b_lin = (const float*)d_in[26];
  float* out = (float*)d_out;

  int N  = in_sizes[4];
  int NC = in_sizes[3] / 27;
  int ntF = (N + 63) / 64, ntC = (NC + 63) / 64;
  int CAPP = ((NC * 9 / 2) / 128 + 28) * 128;   // padded pair capacity

  size_t szF = (size_t)N * 32;
  size_t szG = (size_t)NC * 64;
  size_t SB  = (size_t)N * 64;

  float* ws = (float*)d_ws;
  float* S1 = ws;          // f1 [N,32] -> g2c [NC,64]
  float* S2 = S1 + SB;     // a1 -> acat [N,64]
  float* S3 = S2 + SB;     // f2 [N,32] -> f3 [N,32]
  float* S4 = S3 + szF;    // a2 [N,32] -> u [N,32]
  float* S5 = S4 + szF;    // gC [NC,64] -> au [NC,64]
  float* sums1 = S5 + szG;           // 8*64
  float* sumsD = sums1 + 8 * 64;     // 8*64
  float* sums2 = sumsD + 8 * 64;     // 8*128
  float* sumsU = sums2 + 8 * 128;    // 8*128
  float* sums4 = sumsU + 8 * 128;    // 8*64
  float* sums5 = sums4 + 8 * 64;     // 8*64
  int* ccnt = (int*)(sums5 + 8 * 64);         // NC
  int* cent = ccnt + NC;                      // NC*8
  int* cntF = cent + (size_t)NC * 8;          // N
  int* entF = cntF + N;                       // N*27
  int* kcnt = entF + (size_t)N * 27;          // 32
  int* segSt = kcnt + 32;                     // 32
  int* kfill = segSt + 32;                    // 32
  int* cntC = kfill + 32;                     // NC
  int* posC = cntC + NC;                      // NC*27
  int* entJ = posC + (size_t)NC * 27;         // CAPP
  unsigned short* partials = (unsigned short*)
      (((uintptr_t)(entJ + CAPP) + 15) & ~(uintptr_t)15);  // CAPP*64 bf16

  hipMemsetAsync(sums1, 0, (4096 + NC) * sizeof(float), stream);
  hipMemsetAsync(kcnt, 0, 96 * sizeof(int), stream);
  hipMemsetAsync(entJ, 0, (size_t)CAPP * sizeof(int), stream);

  int gridN = (N + BLK - 1) / BLK;
  int gridC = (NC + BLK - 1) / BLK;
  int agrid = 1024;
  float invN = 1.f / (float)N, invC = 1.f / (float)NC;

  // rulebooks
  build_fine_k<<<ntF, 64, 0, stream>>>(nbrF, N, cntF, entF);
  child_scatter_k<<<gridN, BLK, 0, stream>>>(parent, offid, N, ccnt, cent);
  kcount_k<<<gridC, BLK, 0, stream>>>(nbrC, NC, kcnt);
  kprefix_k<<<1, 32, 0, stream>>>(kcnt, segSt, kfill);
  kscatter_k<<<gridC, BLK, 0, stream>>>(nbrC, NC, kfill, entJ, cntC, posC);

  // conv_in -> f1(S1), stats -> sums1
  conv_in_k<<<gridN, BLK, 0, stream>>>(feat, nbrF, w_in, S1, N, sums1);
  bnact_k<32><<<agrid, BLK, 0, stream>>>(S1, sums1, g1v, b1v, invN, S2, N);   // a1

  // b1: a1 -> f2(S3), stats -> sumsD
  tconvA_k<32, 32, 0><<<ntF, BLK, 0, stream>>>(
      S2, entF, cntF, nullptr, nullptr, w_b1, S3, N, sumsD);
  bnact_k<32><<<agrid, BLK, 0, stream>>>(S3, sumsD, gdv, bdv, invN, S4, N);   // a2

  // down: a2 -> gC(S5), stats -> sums2
  tconvA_k<32, 64, 1><<<ntC, BLK, 0, stream>>>(
      S4, cent, ccnt, nullptr, nullptr, w_down, S5, NC, sums2);

  // b2 pass1: k-uniform pair GEMM (bn2 fused at stage) -> partials
  int gridP1 = CAPP / 128;
  pgemm_k<<<gridP1, 128, 0, stream>>>(
      S5, segSt, entJ, sums2, g2v, b2v, invC, w_b2, partials);
  // b2 pass2: gather partials -> g2c(S1, f1 dead), stats -> sumsU
  pgather_k<<<(NC + 15) / 16, BLK, 0, stream>>>(
      partials, cntC, posC, S1, NC, sumsU);

  bnact_k<64><<<agrid, BLK, 0, stream>>>(S1, sumsU, guv, buv, invC, S5, NC);  // au (gC dead)

  // up: au -> u(S4, a2 dead), stats -> sums4
  tconvA_k<64, 32, 2><<<ntF, BLK, 0, stream>>>(
      S5, nullptr, nullptr, parent, offid, w_up, S4, N, sums4);

  // bncat: (bn(f2)|bn(u)) -> acat(S2, a1 dead)
  bncat_k<<<agrid, BLK, 0, stream>>>(
      S3, sumsD, g3v, b3v, S4, sums4, g3v + 32, b3v + 32, invN, S2, N);

  // b3: acat -> f3(S3, f2 dead), stats -> sums5
  tconvA_k<64, 32, 0><<<ntF, BLK, 0, stream>>>(
      S2, entF, cntF, nullptr, nullptr, w_b3, S3, N, sums5);

  head_k<<<gridN, BLK, 0, stream>>>(S3, sums5, gov, bov, invN, w_lin, b_lin, out, N);
}

// Round 13
// 518.650 us; speedup vs baseline: 1.7262x; 1.0168x over previous
//
#include <hip/hip_runtime.h>

#define EPS_BN 1e-4f
constexpr int BLK = 256;
constexpr int NCOPY = 8;     // stats atomic copies

__global__ __launch_bounds__(BLK) void child_scatter_k(
    const int* __restrict__ parent, const int* __restrict__ offid, int n,
    int* __restrict__ ccnt, int* __restrict__ cent) {
  int i = blockIdx.x * BLK + threadIdx.x;
  if (i >= n) return;
  int p = parent[i];
  int slot = atomicAdd(&ccnt[p], 1);
  cent[p * 8 + slot] = i | (offid[i] << 25);
}

// ---------- k-sort rulebook: count -> padded prefix -> hierarchical scatter ----------
__global__ __launch_bounds__(BLK) void kcount_k(
    const int* __restrict__ nbr, int n, int* __restrict__ kcnt) {
  __shared__ int lc[27];
  int t = threadIdx.x;
  if (t < 27) lc[t] = 0;
  __syncthreads();
  int i = blockIdx.x * BLK + t;
  if (i < n) {
#pragma unroll 1
    for (int k = 0; k < 27; ++k)
      if (nbr[(size_t)i * 27 + k] >= 0) atomicAdd(&lc[k], 1);
  }
  __syncthreads();
  if (t < 27 && lc[t]) atomicAdd(&kcnt[t], lc[t]);
}

__global__ void kprefix_k(const int* __restrict__ kcnt,
                          int* __restrict__ segSt, int* __restrict__ kfill) {
  if (threadIdx.x == 0) {
    int s = 0;
#pragma unroll 1
    for (int k = 0; k < 27; ++k) {
      segSt[k] = s; kfill[k] = s;
      s += (kcnt[k] + 127) & ~127;
    }
    segSt[27] = s;
  }
}

// hierarchical: LDS count -> one global reservation per k per block -> LDS position assign
__global__ __launch_bounds__(BLK) void kscatter_k(
    const int* __restrict__ nbr, int n, int* __restrict__ kfill,
    int* __restrict__ entJ, int* __restrict__ cntR, int* __restrict__ posR) {
  __shared__ int lc[27], lbase[27];
  int t = threadIdx.x;
  if (t < 27) lc[t] = 0;
  __syncthreads();
  int i = blockIdx.x * BLK + t;
  int c = 0;
  if (i < n) {
#pragma unroll 1
    for (int k = 0; k < 27; ++k)
      if (nbr[(size_t)i * 27 + k] >= 0) { atomicAdd(&lc[k], 1); ++c; }
  }
  __syncthreads();
  if (t < 27) {
    lbase[t] = lc[t] ? atomicAdd(&kfill[t], lc[t]) : 0;
    lc[t] = 0;
  }
  __syncthreads();
  if (i < n) {
    int e = 0;
#pragma unroll 1
    for (int k = 0; k < 27; ++k) {
      int j = nbr[(size_t)i * 27 + k];
      if (j >= 0) {
        int pos = lbase[k] + atomicAdd(&lc[k], 1);
        entJ[pos] = j;
        posR[(size_t)i * 27 + e] = pos;
        ++e;
      }
    }
    cntR[i] = c;
  }
}

__device__ __forceinline__ unsigned f2bf(float x) {
  unsigned u = __float_as_uint(x);
  return (u + 0x7FFFu + ((u >> 16) & 1u)) >> 16;
}

// ---------- k-uniform pair GEMM: BN fused at stage, register-tiled ----------
template <int CI, int CO, bool CAT, bool BF>
__global__ __launch_bounds__(128) void pgemm_k(
    const float* __restrict__ inA, const float* __restrict__ inB,
    const int* __restrict__ segSt, const int* __restrict__ entJ,
    const float* __restrict__ sumsA, const float* __restrict__ gmA,
    const float* __restrict__ btA, float invA,
    const float* __restrict__ sumsB, const float* __restrict__ gmB,
    const float* __restrict__ btB, float invB,
    const float* __restrict__ W, void* __restrict__ partials) {
  constexpr int XP = CI + 4;
  constexpr int C4 = CI / 4;
  constexpr int NS = 1024 / CO;   // slots
  constexpr int PP = 128 / NS;    // pairs per thread = lanes per slot
  constexpr int CIA = CAT ? CI / 2 : CI;
  constexpr int WL = CI * CO / 512;
  __shared__ float lw[CI * CO];
  __shared__ float lx[128 * XP];
  __shared__ float lst[2 * CI];
  int t = threadIdx.x;
  int base = blockIdx.x * 128;
  if (base >= segSt[27]) return;
  int k = 0;
#pragma unroll 1
  while (segSt[k + 1] <= base) ++k;
  if (t < CI) {
    const float* S; const float* G; const float* B; float inv; int c;
    if (!CAT || t < CIA) { S = sumsA; G = gmA; B = btA; inv = invA; c = t; }
    else { S = sumsB; G = gmB; B = btB; inv = invB; c = t - CIA; }
    float s = 0.f, q = 0.f;
#pragma unroll
    for (int cp = 0; cp < NCOPY; ++cp) { s += S[cp * 2 * CIA + c]; q += S[cp * 2 * CIA + CIA + c]; }
    float mu = s * inv, var = q * inv - mu * mu;
    float sc = G[c] / sqrtf(var + EPS_BN);
    lst[t] = sc; lst[CI + t] = B[c] - mu * sc;
  }
  const float4* wsrc = reinterpret_cast<const float4*>(W + (size_t)k * (CI * CO));
#pragma unroll
  for (int q = 0; q < WL; ++q)
    reinterpret_cast<float4*>(lw)[t + q * 128] = wsrc[t + q * 128];
  __syncthreads();
  // stage X rows with BN+ReLU
#pragma unroll 1
  for (int it = 0; it < C4; ++it) {
    int idx = t + it * 128;
    int pr = idx / C4, cq = idx % C4;
    int j = entJ[base + pr];
    int cb = cq * 4;
    float4 x;
    if constexpr (CAT) {
      x = (cb < CIA) ? *reinterpret_cast<const float4*>(inA + (size_t)j * CIA + cb)
                     : *reinterpret_cast<const float4*>(inB + (size_t)j * CIA + (cb - CIA));
    } else {
      x = *reinterpret_cast<const float4*>(inA + (size_t)j * CI + cb);
    }
    float y0 = fmaf(x.x, lst[cb + 0], lst[CI + cb + 0]);
    float y1 = fmaf(x.y, lst[cb + 1], lst[CI + cb + 1]);
    float y2 = fmaf(x.z, lst[cb + 2], lst[CI + cb + 2]);
    float y3 = fmaf(x.w, lst[cb + 3], lst[CI + cb + 3]);
    *reinterpret_cast<float4*>(&lx[pr * XP + cb]) =
        make_float4(y0 > 0.f ? y0 : 0.f, y1 > 0.f ? y1 : 0.f,
                    y2 > 0.f ? y2 : 0.f, y3 > 0.f ? y3 : 0.f);
  }
  __syncthreads();
  int slot = t / PP, g = (t % PP) * 8;
  float acc[PP][8];
#pragma unroll
  for (int pp = 0; pp < PP; ++pp)
#pragma unroll
    for (int b = 0; b < 8; ++b) acc[pp][b] = 0.f;
#pragma unroll
  for (int c4 = 0; c4 < C4; ++c4) {
    int cb = c4 * 4;
    float4 xq[PP];
#pragma unroll
    for (int pp = 0; pp < PP; ++pp)
      xq[pp] = *reinterpret_cast<const float4*>(&lx[(slot + NS * pp) * XP + cb]);
#pragma unroll
    for (int q = 0; q < 4; ++q) {
      float4 wa = *reinterpret_cast<const float4*>(&lw[(cb + q) * CO + g]);
      float4 wb = *reinterpret_cast<const float4*>(&lw[(cb + q) * CO + g + 4]);
      float ws[8] = {wa.x, wa.y, wa.z, wa.w, wb.x, wb.y, wb.z, wb.w};
#pragma unroll
      for (int pp = 0; pp < PP; ++pp) {
        float xv = q == 0 ? xq[pp].x : (q == 1 ? xq[pp].y : (q == 2 ? xq[pp].z : xq[pp].w));
#pragma unroll
        for (int b = 0; b < 8; ++b) acc[pp][b] = fmaf(xv, ws[b], acc[pp][b]);
      }
    }
  }
#pragma unroll
  for (int pp = 0; pp < PP; ++pp) {
    size_t p = base + slot + NS * pp;
    if constexpr (BF) {
      uint4 o;
      o.x = f2bf(acc[pp][0]) | (f2bf(acc[pp][1]) << 16);
      o.y = f2bf(acc[pp][2]) | (f2bf(acc[pp][3]) << 16);
      o.z = f2bf(acc[pp][4]) | (f2bf(acc[pp][5]) << 16);
      o.w = f2bf(acc[pp][6]) | (f2bf(acc[pp][7]) << 16);
      *reinterpret_cast<uint4*>((unsigned short*)partials + p * CO + g) = o;
    } else {
      float* pf = (float*)partials + p * CO + g;
      *reinterpret_cast<float4*>(pf) = make_float4(acc[pp][0], acc[pp][1], acc[pp][2], acc[pp][3]);
      *reinterpret_cast<float4*>(pf + 4) = make_float4(acc[pp][4], acc[pp][5], acc[pp][6], acc[pp][7]);
    }
  }
}

// ---------- gather partials per row, fused stats ----------
template <int CO, bool BF>
__global__ __launch_bounds__(BLK) void pgather_k(
    const void* __restrict__ partials, const int* __restrict__ cntR,
    const int* __restrict__ posR, float* __restrict__ out, int n,
    float* __restrict__ osums) {
  constexpr int LPS = CO / 4, RPB = BLK / LPS;
  __shared__ float red[2 * CO];
  int t = threadIdx.x;
  for (int idx = t; idx < 2 * CO; idx += BLK) red[idx] = 0.f;
  __syncthreads();
  int slot = t / LPS, g = (t % LPS) * 4;
  int row = blockIdx.x * RPB + slot;
  float a0 = 0.f, a1 = 0.f, a2 = 0.f, a3 = 0.f;
  if (row < n) {
    int c = cntR[row];
    const int* pr = posR + (size_t)row * 27;
#pragma unroll 1
    for (int e = 0; e < c; ++e) {
      size_t pos = (size_t)pr[e];
      if constexpr (BF) {
        uint2 u = *reinterpret_cast<const uint2*>((const unsigned short*)partials + pos * CO + g);
        a0 += __uint_as_float(u.x << 16);
        a1 += __uint_as_float(u.x & 0xFFFF0000u);
        a2 += __uint_as_float(u.y << 16);
        a3 += __uint_as_float(u.y & 0xFFFF0000u);
      } else {
        float4 v = *reinterpret_cast<const float4*>((const float*)partials + pos * CO + g);
        a0 += v.x; a1 += v.y; a2 += v.z; a3 += v.w;
      }
    }
    *reinterpret_cast<float4*>(out + (size_t)row * CO + g) = make_float4(a0, a1, a2, a3);
  }
  atomicAdd(&red[g + 0], a0); atomicAdd(&red[g + 1], a1);
  atomicAdd(&red[g + 2], a2); atomicAdd(&red[g + 3], a3);
  atomicAdd(&red[CO + g + 0], a0 * a0); atomicAdd(&red[CO + g + 1], a1 * a1);
  atomicAdd(&red[CO + g + 2], a2 * a2); atomicAdd(&red[CO + g + 3], a3 * a3);
  __syncthreads();
  int copy = blockIdx.x & (NCOPY - 1);
  if (t < 2 * CO) atomicAdd(&osums[copy * 2 * CO + t], red[t]);
}

// ---------- Type A: output-stationary register-acc gather (down MODE 1 / up MODE 2) ----------
template <int CI, int CO, int MODE>
__global__ __launch_bounds__(BLK) void tconvA_k(
    const float* __restrict__ in, const int* __restrict__ ent, const int* __restrict__ cnt,
    const int* __restrict__ parent, const int* __restrict__ offid,
    const float* __restrict__ W, float* __restrict__ out, int n,
    float* __restrict__ osums) {
  constexpr int LANES = CO / 4, SLOTS = BLK / LANES, RPS = 64 / SLOTS;
  __shared__ float red[2 * CO];
  int t = threadIdx.x;
  for (int idx = t; idx < 2 * CO; idx += BLK) red[idx] = 0.f;
  __syncthreads();
  int slot = t / LANES, lane = t % LANES, g = lane * 4;
  int T = blockIdx.x;
  float ssum[4] = {0, 0, 0, 0}, ssq[4] = {0, 0, 0, 0};
#pragma unroll 1
  for (int rr = 0; rr < RPS; ++rr) {
    int row = T * 64 + slot * RPS + rr;
    bool vrow = row < n;
    float a0 = 0.f, a1 = 0.f, a2 = 0.f, a3 = 0.f;
    int ec = 0;
    if (vrow) ec = (MODE == 2) ? 1 : cnt[row];
#pragma unroll 1
    for (int e = 0; e < ec; ++e) {
      int k, j;
      if constexpr (MODE == 1) {
        int v = ent[(size_t)row * 8 + e];
        k = v >> 25; j = v & 0x1FFFFFF;
      } else {
        k = offid[row]; j = parent[row];
      }
      const float* Wk = W + (size_t)k * (CI * CO) + g;
      const float* xr = in + (size_t)j * CI;
#pragma unroll
      for (int h = 0; h < CI / 32; ++h) {
        float4 xv[8];
#pragma unroll
        for (int c4 = 0; c4 < 8; ++c4)
          xv[c4] = *reinterpret_cast<const float4*>(xr + h * 32 + c4 * 4);
#pragma unroll
        for (int c4 = 0; c4 < 8; ++c4) {
          float xs[4] = {xv[c4].x, xv[c4].y, xv[c4].z, xv[c4].w};
#pragma unroll
          for (int q = 0; q < 4; ++q) {
            float4 wv = *reinterpret_cast<const float4*>(Wk + (size_t)(h * 32 + c4 * 4 + q) * CO);
            a0 = fmaf(xs[q], wv.x, a0);
            a1 = fmaf(xs[q], wv.y, a1);
            a2 = fmaf(xs[q], wv.z, a2);
            a3 = fmaf(xs[q], wv.w, a3);
          }
        }
      }
    }
    if (vrow)
      *reinterpret_cast<float4*>(out + (size_t)row * CO + g) = make_float4(a0, a1, a2, a3);
    ssum[0] += a0; ssum[1] += a1; ssum[2] += a2; ssum[3] += a3;
    ssq[0] = fmaf(a0, a0, ssq[0]); ssq[1] = fmaf(a1, a1, ssq[1]);
    ssq[2] = fmaf(a2, a2, ssq[2]); ssq[3] = fmaf(a3, a3, ssq[3]);
  }
#pragma unroll
  for (int q = 0; q < 4; ++q) {
    atomicAdd(&red[g + q], ssum[q]);
    atomicAdd(&red[CO + g + q], ssq[q]);
  }
  __syncthreads();
  int copy = blockIdx.x & (NCOPY - 1);
  if (t < 2 * CO) atomicAdd(&osums[copy * 2 * CO + t], red[t]);
}

// ---------- bnact: finalize(8 copies) + relu(x*scale+shift) ----------
template <int C>
__global__ __launch_bounds__(BLK) void bnact_k(
    const float* __restrict__ in, const float* __restrict__ sums,
    const float* __restrict__ gm, const float* __restrict__ bt, float invn,
    float* __restrict__ outp, int n) {
  __shared__ float lst[2 * C];
  int t = threadIdx.x;
  if (t < C) {
    float s = 0.f, q = 0.f;
#pragma unroll
    for (int cp = 0; cp < NCOPY; ++cp) { s += sums[cp * 2 * C + t]; q += sums[cp * 2 * C + C + t]; }
    float mu = s * invn, var = q * invn - mu * mu;
    float sc = gm[t] / sqrtf(var + EPS_BN);
    lst[t] = sc; lst[C + t] = bt[t] - mu * sc;
  }
  __syncthreads();
  int total = n * (C / 4);
  const float4* in4 = reinterpret_cast<const float4*>(in);
  float4* out4 = reinterpret_cast<float4*>(outp);
  for (int idx = blockIdx.x * BLK + t; idx < total; idx += gridDim.x * BLK) {
    int cb = (idx & (C / 4 - 1)) * 4;
    float4 x = in4[idx];
    float v[4] = {x.x, x.y, x.z, x.w};
#pragma unroll
    for (int q = 0; q < 4; ++q) {
      float y = fmaf(v[q], lst[cb + q], lst[C + cb + q]);
      v[q] = y > 0.f ? y : 0.f;
    }
    out4[idx] = make_float4(v[0], v[1], v[2], v[3]);
  }
}

// ---------------- conv_in: [N,3] x [27,3,32] -> [N,32], fused stats ----------------
__global__ __launch_bounds__(BLK) void conv_in_k(
    const float* __restrict__ feat, const int* __restrict__ nbr,
    const float* __restrict__ W, float* __restrict__ out, int n,
    float* __restrict__ osums) {
  int i = blockIdx.x * BLK + threadIdx.x;
  bool valid = i < n;
  float acc[32];
#pragma unroll
  for (int c = 0; c < 32; ++c) acc[c] = 0.f;
#pragma unroll 1
  for (int k = 0; k < 27; ++k) {
    int j = valid ? nbr[(size_t)i * 27 + k] : -1;
    if (j < 0) continue;
    float x0 = feat[j * 3 + 0], x1 = feat[j * 3 + 1], x2 = feat[j * 3 + 2];
    const float* w0 = W + k * 96;
#pragma unroll
    for (int co = 0; co < 8; ++co) {
      float4 a = *reinterpret_cast<const float4*>(w0 + co * 4);
      float4 b = *reinterpret_cast<const float4*>(w0 + 32 + co * 4);
      float4 cc = *reinterpret_cast<const float4*>(w0 + 64 + co * 4);
      acc[4*co+0] = fmaf(x0, a.x, fmaf(x1, b.x, fmaf(x2, cc.x, acc[4*co+0])));
      acc[4*co+1] = fmaf(x0, a.y, fmaf(x1, b.y, fmaf(x2, cc.y, acc[4*co+1])));
      acc[4*co+2] = fmaf(x0, a.z, fmaf(x1, b.z, fmaf(x2, cc.z, acc[4*co+2])));
      acc[4*co+3] = fmaf(x0, a.w, fmaf(x1, b.w, fmaf(x2, cc.w, acc[4*co+3])));
    }
  }
  if (valid) {
    float* o = out + (size_t)i * 32;
#pragma unroll
    for (int co = 0; co < 8; ++co)
      *reinterpret_cast<float4*>(o + co * 4) = make_float4(acc[4*co], acc[4*co+1], acc[4*co+2], acc[4*co+3]);
  }
  __shared__ float red[2][4][32];
  int w = threadIdx.x >> 6;
#pragma unroll
  for (int c = 0; c < 32; ++c) {
    float v = acc[c], q = acc[c] * acc[c];
#pragma unroll
    for (int off = 32; off; off >>= 1) {
      v += __shfl_down(v, off);
      q += __shfl_down(q, off);
    }
    if ((threadIdx.x & 63) == 0) { red[0][w][c] = v; red[1][w][c] = q; }
  }
  __syncthreads();
  if (threadIdx.x < 64) {
    int kind = threadIdx.x >> 5, c = threadIdx.x & 31;
    float s = red[kind][0][c] + red[kind][1][c] + red[kind][2][c] + red[kind][3][c];
    atomicAdd(&osums[(blockIdx.x & (NCOPY - 1)) * 64 + kind * 32 + c], s);
  }
}

// ---------------- head: finalize(8 copies) + bn @ w_lin + b_lin -> [N,50] ----------------
__global__ __launch_bounds__(BLK) void head_k(
    const float* __restrict__ fin, const float* __restrict__ sums,
    const float* __restrict__ gm, const float* __restrict__ bt, float inv_n,
    const float* __restrict__ Wl, const float* __restrict__ bl,
    float* __restrict__ out, int n) {
  __shared__ float lw[32 * 50];
  __shared__ float lb[52];
  __shared__ float lst[64];
  int t = threadIdx.x;
  if (t < 32) {
    float s = 0.f, q = 0.f;
#pragma unroll
    for (int cp = 0; cp < NCOPY; ++cp) { s += sums[cp * 64 + t]; q += sums[cp * 64 + 32 + t]; }
    float mu = s * inv_n, var = q * inv_n - mu * mu;
    float sc = gm[t] / sqrtf(var + EPS_BN);
    lst[t] = sc; lst[32 + t] = bt[t] - mu * sc;
  }
  for (int idx = t; idx < 1600; idx += BLK) lw[idx] = Wl[idx];
  if (t < 50) lb[t] = bl[t];
  __syncthreads();
  int i = blockIdx.x * BLK + t;
  if (i >= n) return;
  float x[32];
  const float* fj = fin + (size_t)i * 32;
#pragma unroll
  for (int c4 = 0; c4 < 8; ++c4) {
    float4 v = *reinterpret_cast<const float4*>(fj + c4 * 4);
    float vs[4] = {v.x, v.y, v.z, v.w};
#pragma unroll
    for (int q = 0; q < 4; ++q) {
      int c = c4 * 4 + q;
      float y = fmaf(vs[q], lst[c], lst[32 + c]);
      x[c] = y > 0.f ? y : 0.f;
    }
  }
  float acc[50];
#pragma unroll
  for (int co = 0; co < 50; ++co) acc[co] = lb[co];
#pragma unroll 4
  for (int c = 0; c < 32; ++c) {
#pragma unroll
    for (int co = 0; co < 50; ++co) acc[co] = fmaf(x[c], lw[c * 50 + co], acc[co]);
  }
  float* o = out + (size_t)i * 50;
#pragma unroll
  for (int co = 0; co < 25; ++co)
    *reinterpret_cast<float2*>(o + co * 2) = make_float2(acc[co * 2], acc[co * 2 + 1]);
}

extern "C" void kernel_launch(void* const* d_in, const int* in_sizes, int n_in,
                              void* d_out, int out_size, void* d_ws, size_t ws_size,
                              hipStream_t stream) {
  const float* feat   = (const float*)d_in[1];
  const int*   nbrF   = (const int*)d_in[2];
  const int*   nbrC   = (const int*)d_in[3];
  const int*   parent = (const int*)d_in[4];
  const int*   offid  = (const int*)d_in[5];
  const float* w_in   = (const float*)d_in[7];
  const float* w_b1   = (const float*)d_in[8];
  const float* w_down = (const float*)d_in[9];
  const float* w_b2   = (const float*)d_in[10];
  const float* w_up   = (const float*)d_in[11];
  const float* w_b3   = (const float*)d_in[12];
  const float* g1v = (const float*)d_in[13], *b1v = (const float*)d_in[14];
  const float* gdv = (const float*)d_in[15], *bdv = (const float*)d_in[16];
  const float* g2v = (const float*)d_in[17], *b2v = (const float*)d_in[18];
  const float* guv = (const float*)d_in[19], *buv = (const float*)d_in[20];
  const float* g3v = (const float*)d_in[21], *b3v = (const float*)d_in[22];
  const float* gov = (const float*)d_in[23], *bov = (const float*)d_in[24];
  const float* w_lin = (const float*)d_in[25];
  const float* b_lin = (const float*)d_in[26];
  float* out = (float*)d_out;

  int N  = in_sizes[4];
  int NC = in_sizes[3] / 27;
  int ntF = (N + 63) / 64, ntC = (NC + 63) / 64;
  int CAPPF = ((N * 3) / 128 + 28) * 128;        // fine pair cap (expect ~1.37N)
  int CAPPC = ((NC * 9 / 2) / 128 + 28) * 128;   // coarse pair cap

  float* ws = (float*)d_ws;
  float* B1 = ws;                       // f1 [N,32] -> u [N,32]
  float* B2 = B1 + (size_t)N * 32;      // f2 [N,32]
  float* B3 = B2 + (size_t)N * 32;      // a2 [N,32] -> f3 [N,32]
  float* B4 = B3 + (size_t)N * 32;      // gC [NC,64] -> g2c [NC,64]
  float* B5 = B4 + (size_t)NC * 64;     // au [NC,64]
  float* sums1 = B5 + (size_t)NC * 64;  // 8*64
  float* sumsD = sums1 + 8 * 64;        // 8*64
  float* sums2 = sumsD + 8 * 64;        // 8*128
  float* sumsU = sums2 + 8 * 128;       // 8*128
  float* sums4 = sumsU + 8 * 128;       // 8*64
  float* sums5 = sums4 + 8 * 64;        // 8*64
  int* ccnt = (int*)(sums5 + 8 * 64);         // NC
  int* kcntF = ccnt + NC;                     // 32
  int* kcntC = kcntF + 32;                    // 32  (memset covers sums..kcntC)
  int* segStF = kcntC + 32;                   // 32
  int* kfillF = segStF + 32;                  // 32
  int* segStC = kfillF + 32;                  // 32
  int* kfillC = segStC + 32;                  // 32
  int* cent = kfillC + 32;                    // NC*8
  int* cntF = cent + (size_t)NC * 8;          // N
  int* posF = cntF + N;                       // N*27
  int* cntC = posF + (size_t)N * 27;          // NC
  int* posC = cntC + NC;                      // NC*27
  int* entJF = posC + (size_t)NC * 27;        // CAPPF
  int* entJC = entJF + CAPPF;                 // CAPPC
  float* partialsF = (float*)(((uintptr_t)(entJC + CAPPC) + 15) & ~(uintptr_t)15);  // CAPPF*32 f32
  unsigned short* partialsC = (unsigned short*)(partialsF + (size_t)CAPPF * 32);    // CAPPC*64 bf16

  hipMemsetAsync(sums1, 0, (4096 + NC + 64) * sizeof(float), stream);
  hipMemsetAsync(entJF, 0, (size_t)(CAPPF + CAPPC) * sizeof(int), stream);

  int gridN = (N + BLK - 1) / BLK;
  int gridC = (NC + BLK - 1) / BLK;
  int agrid = 1024;
  float invN = 1.f / (float)N, invC = 1.f / (float)NC;

  // rulebooks
  kcount_k<<<gridN, BLK, 0, stream>>>(nbrF, N, kcntF);
  kcount_k<<<gridC, BLK, 0, stream>>>(nbrC, NC, kcntC);
  kprefix_k<<<1, 32, 0, stream>>>(kcntF, segStF, kfillF);
  kprefix_k<<<1, 32, 0, stream>>>(kcntC, segStC, kfillC);
  kscatter_k<<<gridN, BLK, 0, stream>>>(nbrF, N, kfillF, entJF, cntF, posF);
  kscatter_k<<<gridC, BLK, 0, stream>>>(nbrC, NC, kfillC, entJC, cntC, posC);
  child_scatter_k<<<gridN, BLK, 0, stream>>>(parent, offid, N, ccnt, cent);

  // conv_in -> f1(B1), stats -> sums1
  conv_in_k<<<gridN, BLK, 0, stream>>>(feat, nbrF, w_in, B1, N, sums1);

  // b1: bn1(f1) @ w_b1 (k-sorted pgemm) -> partialsF -> f2(B2), stats -> sumsD
  pgemm_k<32, 32, false, false><<<CAPPF / 128, 128, 0, stream>>>(
      B1, nullptr, segStF, entJF, sums1, g1v, b1v, invN,
      nullptr, nullptr, nullptr, 0.f, w_b1, partialsF);
  pgather_k<32, false><<<(N + 31) / 32, BLK, 0, stream>>>(
      partialsF, cntF, posF, B2, N, sumsD);
  bnact_k<32><<<agrid, BLK, 0, stream>>>(B2, sumsD, gdv, bdv, invN, B3, N);  // a2

  // down: a2 -> gC(B4), stats -> sums2
  tconvA_k<32, 64, 1><<<ntC, BLK, 0, stream>>>(
      B3, cent, ccnt, nullptr, nullptr, w_down, B4, NC, sums2);

  // b2: bn2(gC) @ w_b2 (k-sorted pgemm, bf16 partials) -> g2c(B4 in place), stats -> sumsU
  pgemm_k<64, 64, false, true><<<CAPPC / 128, 128, 0, stream>>>(
      B4, nullptr, segStC, entJC, sums2, g2v, b2v, invC,
      nullptr, nullptr, nullptr, 0.f, w_b2, partialsC);
  pgather_k<64, true><<<(NC + 15) / 16, BLK, 0, stream>>>(
      partialsC, cntC, posC, B4, NC, sumsU);
  bnact_k<64><<<agrid, BLK, 0, stream>>>(B4, sumsU, guv, buv, invC, B5, NC);  // au

  // up: au -> u(B1, f1 dead), stats -> sums4
  tconvA_k<64, 32, 2><<<ntF, BLK, 0, stream>>>(
      B5, nullptr, nullptr, parent, offid, w_up, B1, N, sums4);

  // b3: [bn3a(f2)|bn3b(u)] @ w_b3 (CAT pgemm) -> partialsF -> f3(B3, a2 dead), stats -> sums5
  pgemm_k<64, 32, true, false><<<CAPPF / 128, 128, 0, stream>>>(
      B2, B1, segStF, entJF, sumsD, g3v, b3v, invN,
      sums4, g3v + 32, b3v + 32, invN, w_b3, partialsF);
  pgather_k<32, false><<<(N + 31) / 32, BLK, 0, stream>>>(
      partialsF, cntF, posF, B3, N, sums5);

  head_k<<<gridN, BLK, 0, stream>>>(B3, sums5, gov, bov, invN, w_lin, b_lin, out, N);
}